// Round 3
// baseline (244.581 us; speedup 1.0000x reference)
//
#include <hip/hip_runtime.h>
#include <math.h>

// (256, 4096, 33) f32 rows: [K, w1[0..31]]; K passes through; w1 gets
// 4x (31-step push-apart scan + clip). One thread per row.
//
// R1/R2 post-mortem: bulk-sync load/barrier/compute/barrier/store blocks
// convoy -> identical 84 us at 31% HBM regardless of occupancy (4 vs 9
// blocks/CU). Fix: make memory demand continuous via a per-wave software
// pipeline. Single-wave (64-thr) persistent blocks -> NO barriers (so no
// vmcnt(0) drain); double-buffered global_load_lds prefetch; hand-rolled
// s_waitcnt vmcnt(N) (asm volatile + memory clobber = compiler can't
// reorder LDS reads above it). vmcnt retires in order: at the wait in a
// middle iter the queue is [DMA(i) 9][stores(i-1) >=9][DMA(i+1) 9], so
// vmcnt(18) guarantees DMA(i) landed without draining prefetch/stores.
// Store splitting can only over-wait (safe), never under-wait.

#define ROW 33
#define LANES 64
#define TILE_F (LANES * ROW)      // 2112 floats = 8448 B per tile
#define TILE_V4 (TILE_F / 4)      // 528 float4 (8*64 + 16 tail)
#define TPB 8                     // tiles per block

typedef const __attribute__((address_space(1))) unsigned int* gas_p;
typedef __attribute__((address_space(3))) unsigned int* las_p;

__device__ __forceinline__ void dma_tile(gas_p g, las_p s, int lane) {
    // 9 global_load_lds_dwordx4 per tile; LDS dest = wave-uniform base +
    // lane*16 (contiguous), the required DMA pattern.
#pragma unroll
    for (int j = 0; j < 8; ++j)
        __builtin_amdgcn_global_load_lds(g + (size_t)(lane + j * 64) * 4,
                                         s + (size_t)(lane + j * 64) * 4,
                                         16, 0, 0);
    if (lane < (TILE_V4 - 512))
        __builtin_amdgcn_global_load_lds(g + (size_t)(lane + 512) * 4,
                                         s + (size_t)(lane + 512) * 4,
                                         16, 0, 0);
}

__global__ __launch_bounds__(64) void lsp_stability_kernel(
    const float* __restrict__ in, float* __restrict__ out)
{
    __shared__ alignas(16) float smem[2][TILE_F];   // 16.9 KB -> 8+ blocks/CU
    const int lane = threadIdx.x;
    const long long t0 = (long long)blockIdx.x * TPB;

    const float MIND = (float)(0.01 * M_PI / 33.0);
    const float HI = (float)M_PI - MIND;

    dma_tile((gas_p)(in + t0 * TILE_F), (las_p)&smem[0][0], lane);

#pragma unroll 1
    for (int i = 0; i < TPB; ++i) {
        if (i + 1 < TPB)
            dma_tile((gas_p)(in + (t0 + i + 1) * TILE_F),
                     (las_p)&smem[(i + 1) & 1][0], lane);

        // Wait for tile i's 9 DMA ops only (never a full drain).
        if (i == 0)            asm volatile("s_waitcnt vmcnt(9)" ::: "memory");
        else if (i + 1 < TPB)  asm volatile("s_waitcnt vmcnt(18)" ::: "memory");
        else                   asm volatile("s_waitcnt vmcnt(9)" ::: "memory");

        float* buf = smem[i & 1];
        float* row = buf + lane * ROW;   // stride 33 -> 2-way bank alias, free

        float w[32];
#pragma unroll
        for (int k = 0; k < 32; ++k) w[k] = row[k + 1];

#pragma unroll
        for (int it = 0; it < 4; ++it) {
            float c = w[0];
#pragma unroll
            for (int k = 1; k < 32; ++k) {
                float nxt = w[k];
                float sft = 0.5f * fmaxf(MIND - (nxt - c), 0.0f);
                w[k - 1] = c - sft;
                c = nxt + sft;
            }
            w[31] = c;
#pragma unroll
            for (int k = 0; k < 32; ++k)
                w[k] = fminf(fmaxf(w[k], MIND), HI);
        }

        // K (element 0) untouched in LDS; write back w1 only.
#pragma unroll
        for (int k = 0; k < 32; ++k) row[k + 1] = w[k];

        // Coalesced store; ds_read lgkm-waits (compiler) order these after
        // the ds_writes above, so the buffer is clean before its next DMA.
        float4* o4 = (float4*)(out + (t0 + i) * TILE_F);
        const float4* b4 = (const float4*)buf;
#pragma unroll
        for (int j = 0; j < 8; ++j)
            o4[lane + j * 64] = b4[lane + j * 64];
        if (lane < (TILE_V4 - 512))
            o4[lane + 512] = b4[lane + 512];
    }
}

extern "C" void kernel_launch(void* const* d_in, const int* in_sizes, int n_in,
                              void* d_out, int out_size, void* d_ws, size_t ws_size,
                              hipStream_t stream) {
    const float* in = (const float*)d_in[0];
    float* out = (float*)d_out;
    // 34,603,008 floats = 16384 tiles of 2112 -> 2048 blocks x 8 tiles.
    const int blocks = in_sizes[0] / (TILE_F * TPB);
    lsp_stability_kernel<<<blocks, LANES, 0, stream>>>(in, out);
}